// Round 1
// baseline (814.989 us; speedup 1.0000x reference)
//
#include <hip/hip_runtime.h>
#include <stdint.h>

// ---------------------------------------------------------------------------
// Dual attention (DANet): pos attention + channel attention, fused pipeline.
// B=8, C=512, CQ=64, H=W=64, HW=4096.  All GEMMs bf16 MFMA 16x16x32, fp32 acc.
//
// pos_out[c,j] = sum_i v'[c,i] * exp(e[i,j]),  v' = (Wv x + b) * rcp_l[i],
//   rcp_l[i] = 1 / sum_j exp(e[i,j])   (no max subtraction: |e| <~ 13)
// Pass 2 is flash-style: recompute E block (K=64 MFMA), exp -> bf16 LDS
// (B-operand layout), PV MFMA. No 537MB energy materialization.
// ---------------------------------------------------------------------------

#define LOG2E 1.44269504088896340736f

typedef __attribute__((ext_vector_type(8))) __bf16 bf16x8;
typedef __attribute__((ext_vector_type(4))) float floatx4;
typedef __attribute__((ext_vector_type(2))) float floatx2;
typedef __attribute__((ext_vector_type(4))) unsigned short ushort4v;

static __device__ __forceinline__ unsigned short f2bf(float f) {
    union { float f; uint32_t u; } v; v.f = f;
    uint32_t r = v.u + 0x7fffu + ((v.u >> 16) & 1u);   // RNE
    return (unsigned short)(r >> 16);
}

// ---------------------------------------------------------------------------
// Generic TN GEMM: C[m,n] = sum_k A[m,k]*B[n,k] (+bias_m[m]) (+bias_n[n]),
// then * scale_n[n].  A,B bf16 row-major K-contiguous. BK=64 fixed.
// ---------------------------------------------------------------------------
template<int BM, int BN, bool OUT_BF16, bool ATOMIC>
__global__ __launch_bounds__(256) void tn_gemm(
    const unsigned short* __restrict__ A, int lda, long sA,
    const unsigned short* __restrict__ B, int ldb, long sB,
    void* __restrict__ C, int ldc, long sC,
    const float* __restrict__ bias_m, const float* __restrict__ bias_n,
    const float* __restrict__ scale_n, long sScale,
    int K, int kchunks)
{
    constexpr int PK = 72;                 // 64 + 8 pad: 2-way bank alias only
    __shared__ unsigned short As[BM * PK];
    __shared__ unsigned short Bs[BN * PK];
    const int bz = blockIdx.z;
    const int b  = bz / kchunks;
    const int kc = bz % kchunks;
    const int m0 = blockIdx.y * BM;
    const int n0 = blockIdx.x * BN;
    const unsigned short* Ab = A + (long)b * sA + (long)m0 * lda + (long)kc * K;
    const unsigned short* Bb = B + (long)b * sB + (long)n0 * ldb + (long)kc * K;
    const int tid = threadIdx.x;
    const int lane = tid & 63, wave = tid >> 6;
    const int l15 = lane & 15, quad = lane >> 4;
    constexpr int NT  = BN / 16;
    constexpr int MPW = BM / 64;           // m-tiles per wave
    constexpr int AL  = BM / 32;           // dwordx4 staging loads per thread
    constexpr int BL  = BN / 32;

    const floatx4 vz = {0.f, 0.f, 0.f, 0.f};
    floatx4 acc[MPW][NT];
    for (int i = 0; i < MPW; ++i) for (int j = 0; j < NT; ++j) acc[i][j] = vz;

    const int nK = K >> 6;
    for (int k0 = 0; k0 < nK; ++k0) {
        floatx4 ar[AL], br[BL];
#pragma unroll
        for (int L = 0; L < AL; ++L) {
            int flat = L * 2048 + tid * 8;
            ar[L] = *(const floatx4*)(Ab + (long)(flat >> 6) * lda + (k0 << 6) + (flat & 63));
        }
#pragma unroll
        for (int L = 0; L < BL; ++L) {
            int flat = L * 2048 + tid * 8;
            br[L] = *(const floatx4*)(Bb + (long)(flat >> 6) * ldb + (k0 << 6) + (flat & 63));
        }
        __syncthreads();
#pragma unroll
        for (int L = 0; L < AL; ++L) {
            int flat = L * 2048 + tid * 8;
            *(floatx4*)&As[(flat >> 6) * PK + (flat & 63)] = ar[L];
        }
#pragma unroll
        for (int L = 0; L < BL; ++L) {
            int flat = L * 2048 + tid * 8;
            *(floatx4*)&Bs[(flat >> 6) * PK + (flat & 63)] = br[L];
        }
        __syncthreads();
#pragma unroll
        for (int ks = 0; ks < 2; ++ks) {
            bf16x8 af[MPW];
#pragma unroll
            for (int mi = 0; mi < MPW; ++mi)
                af[mi] = *(const bf16x8*)&As[((wave * MPW + mi) * 16 + l15) * PK + ks * 32 + quad * 8];
#pragma unroll
            for (int nt = 0; nt < NT; ++nt) {
                bf16x8 bf = *(const bf16x8*)&Bs[(nt * 16 + l15) * PK + ks * 32 + quad * 8];
#pragma unroll
                for (int mi = 0; mi < MPW; ++mi)
                    acc[mi][nt] = __builtin_amdgcn_mfma_f32_16x16x32_bf16(af[mi], bf, acc[mi][nt], 0, 0, 0);
            }
        }
    }
    // epilogue (C/D layout: col = lane&15, row = quad*4 + r)
#pragma unroll
    for (int mi = 0; mi < MPW; ++mi) {
        const int mb = m0 + (wave * MPW + mi) * 16 + quad * 4;
#pragma unroll
        for (int nt = 0; nt < NT; ++nt) {
            const int n = n0 + nt * 16 + l15;
            const float bn = bias_n ? bias_n[n] : 0.f;
            const float cs = scale_n ? scale_n[(long)b * sScale + n] : 1.f;
            floatx4 a = acc[mi][nt];
#pragma unroll
            for (int r = 0; r < 4; ++r) {
                const int m = mb + r;
                float v = (a[r] + (bias_m ? bias_m[m] : 0.f) + bn) * cs;
                const long idx = (long)b * sC + (long)m * ldc + n;
                if (ATOMIC)         atomicAdd((float*)C + idx, v);
                else if (OUT_BF16)  ((unsigned short*)C)[idx] = f2bf(v);
                else                ((float*)C)[idx] = v;
            }
        }
    }
}

// ---------------------------------------------------------------------------
// rcp_l[b,i] = 1 / sum_j exp(E[i,j]); E block via MFMA (qT staged in LDS,
// kT B-fragments straight from global).
// ---------------------------------------------------------------------------
__global__ __launch_bounds__(256) void rowsum_kernel(
    const unsigned short* __restrict__ qT, const unsigned short* __restrict__ kT,
    float* __restrict__ rcl)
{
    __shared__ unsigned short Qs[128 * 72];
    const int b  = blockIdx.z;
    const int i0 = blockIdx.x * 128;
    const unsigned short* qb = qT + ((long)b * 4096 + i0) * 64;
    const unsigned short* kb = kT + (long)b * 4096 * 64;
    const int tid = threadIdx.x, lane = tid & 63, wave = tid >> 6;
    const int l15 = lane & 15, quad = lane >> 4;
#pragma unroll
    for (int L = 0; L < 4; ++L) {
        int flat = L * 2048 + tid * 8;
        *(floatx4*)&Qs[(flat >> 6) * 72 + (flat & 63)] =
            *(const floatx4*)(qb + (long)(flat >> 6) * 64 + (flat & 63));
    }
    __syncthreads();
    bf16x8 af[2][2];
#pragma unroll
    for (int mi = 0; mi < 2; ++mi)
#pragma unroll
        for (int ks = 0; ks < 2; ++ks)
            af[mi][ks] = *(const bf16x8*)&Qs[((wave * 2 + mi) * 16 + l15) * 72 + ks * 32 + quad * 8];

    float rs[2][4];
    for (int mi = 0; mi < 2; ++mi) for (int r = 0; r < 4; ++r) rs[mi][r] = 0.f;
    const floatx4 vz = {0.f, 0.f, 0.f, 0.f};
    for (int jb = 0; jb < 32; ++jb) {
        const unsigned short* kblk = kb + (long)jb * 128 * 64;
        floatx4 e[2][8];
        for (int mi = 0; mi < 2; ++mi) for (int nt = 0; nt < 8; ++nt) e[mi][nt] = vz;
#pragma unroll
        for (int ks = 0; ks < 2; ++ks)
#pragma unroll
            for (int nt = 0; nt < 8; ++nt) {
                bf16x8 bf = *(const bf16x8*)(kblk + (long)((nt * 16 + l15) * 64) + ks * 32 + quad * 8);
#pragma unroll
                for (int mi = 0; mi < 2; ++mi)
                    e[mi][nt] = __builtin_amdgcn_mfma_f32_16x16x32_bf16(af[mi][ks], bf, e[mi][nt], 0, 0, 0);
            }
#pragma unroll
        for (int mi = 0; mi < 2; ++mi)
#pragma unroll
            for (int nt = 0; nt < 8; ++nt)
#pragma unroll
                for (int r = 0; r < 4; ++r)
                    rs[mi][r] += exp2f(e[mi][nt][r] * LOG2E);
    }
#pragma unroll
    for (int mi = 0; mi < 2; ++mi)
#pragma unroll
        for (int r = 0; r < 4; ++r) {
            float v = rs[mi][r];
            v += __shfl_xor(v, 1); v += __shfl_xor(v, 2);
            v += __shfl_xor(v, 4); v += __shfl_xor(v, 8);
            if (l15 == 0)
                rcl[(long)b * 4096 + i0 + (wave * 2 + mi) * 16 + quad * 4 + r] = 1.0f / v;
        }
}

// ---------------------------------------------------------------------------
// Fused position attention pass 2: out[c,j] += sum_i v'[c,i]*exp(E[i,j]).
// Per block: (jtile 128, ctile 128, batch). kT tile LDS-resident; qT/v'
// A-fragments direct from global (LLC-resident); P tile round-trips LDS.
// ---------------------------------------------------------------------------
__global__ __launch_bounds__(256) void pos_attn_kernel(
    const unsigned short* __restrict__ qT, const unsigned short* __restrict__ kT,
    const unsigned short* __restrict__ vP, float* __restrict__ out)
{
    __shared__ unsigned short Ks[128 * 72];
    __shared__ unsigned short Ps[128 * 136];   // P^T [j][i], +8 pad
    const int b  = blockIdx.z;
    const int j0 = blockIdx.x * 128;
    const int c0 = blockIdx.y * 128;
    const unsigned short* qb = qT + (long)b * 4096 * 64;
    const unsigned short* kb = kT + ((long)b * 4096 + j0) * 64;
    const unsigned short* vb = vP + ((long)b * 512 + c0) * 4096;
    const int tid = threadIdx.x, lane = tid & 63, wave = tid >> 6;
    const int l15 = lane & 15, quad = lane >> 4;
#pragma unroll
    for (int L = 0; L < 4; ++L) {
        int flat = L * 2048 + tid * 8;
        *(floatx4*)&Ks[(flat >> 6) * 72 + (flat & 63)] =
            *(const floatx4*)(kb + (long)(flat >> 6) * 64 + (flat & 63));
    }
    const floatx4 vz = {0.f, 0.f, 0.f, 0.f};
    floatx4 oacc[2][8];
    for (int mi = 0; mi < 2; ++mi) for (int nt = 0; nt < 8; ++nt) oacc[mi][nt] = vz;
    __syncthreads();

    for (int ib = 0; ib < 32; ++ib) {
        const unsigned short* qblk = qb + (long)ib * 128 * 64;
        // --- E = Q^T K block (m=i, n=j, k=c; K=64) ---
        floatx4 e[2][8];
        for (int mi = 0; mi < 2; ++mi) for (int nt = 0; nt < 8; ++nt) e[mi][nt] = vz;
#pragma unroll
        for (int ks = 0; ks < 2; ++ks) {
            bf16x8 af[2];
#pragma unroll
            for (int mi = 0; mi < 2; ++mi)
                af[mi] = *(const bf16x8*)(qblk + (long)(((wave * 2 + mi) * 16 + l15) * 64) + ks * 32 + quad * 8);
#pragma unroll
            for (int nt = 0; nt < 8; ++nt) {
                bf16x8 bf = *(const bf16x8*)&Ks[(nt * 16 + l15) * 72 + ks * 32 + quad * 8];
#pragma unroll
                for (int mi = 0; mi < 2; ++mi)
                    e[mi][nt] = __builtin_amdgcn_mfma_f32_16x16x32_bf16(af[mi], bf, e[mi][nt], 0, 0, 0);
            }
        }
        __syncthreads();   // previous PV done reading Ps
        // --- P^T = exp(E) -> bf16 LDS (4 consecutive i rows pack to b64) ---
#pragma unroll
        for (int mi = 0; mi < 2; ++mi) {
            const int il = (wave * 2 + mi) * 16 + quad * 4;
#pragma unroll
            for (int nt = 0; nt < 8; ++nt) {
                ushort4v p;
#pragma unroll
                for (int r = 0; r < 4; ++r) p[r] = f2bf(exp2f(e[mi][nt][r] * LOG2E));
                *(ushort4v*)&Ps[(nt * 16 + l15) * 136 + il] = p;
            }
        }
        __syncthreads();
        // --- out += V' * P (m=c, n=j, k=i; K=128) ---
#pragma unroll
        for (int ks = 0; ks < 4; ++ks) {
            bf16x8 af[2];
#pragma unroll
            for (int mi = 0; mi < 2; ++mi)
                af[mi] = *(const bf16x8*)(vb + (long)((wave * 2 + mi) * 16 + l15) * 4096 + ib * 128 + ks * 32 + quad * 8);
#pragma unroll
            for (int nt = 0; nt < 8; ++nt) {
                bf16x8 bf = *(const bf16x8*)&Ps[(nt * 16 + l15) * 136 + ks * 32 + quad * 8];
#pragma unroll
                for (int mi = 0; mi < 2; ++mi)
                    oacc[mi][nt] = __builtin_amdgcn_mfma_f32_16x16x32_bf16(af[mi], bf, oacc[mi][nt], 0, 0, 0);
            }
        }
    }
    // epilogue: out += pos contribution (chan_out already stored there)
#pragma unroll
    for (int mi = 0; mi < 2; ++mi) {
        const int c = c0 + (wave * 2 + mi) * 16 + quad * 4;
#pragma unroll
        for (int nt = 0; nt < 8; ++nt) {
            const int j = j0 + nt * 16 + l15;
#pragma unroll
            for (int r = 0; r < 4; ++r) {
                const long idx = ((long)b * 512 + c + r) * 4096 + j;
                out[idx] += oacc[mi][nt][r];
            }
        }
    }
}

// ---------------------------------------------------------------------------
// x [B,512,4096] fp32 -> xT [B,4096,512] bf16 (64x64 LDS tile transpose)
// ---------------------------------------------------------------------------
__global__ __launch_bounds__(256) void transpose_x(
    const float* __restrict__ x, unsigned short* __restrict__ xT)
{
    __shared__ unsigned short T[64 * 66];
    const int b  = blockIdx.z;
    const int n0 = blockIdx.x * 64;
    const int c0 = blockIdx.y * 64;
    const int tid = threadIdx.x;
    const int r8 = tid >> 5;
    const int col2 = (tid & 31) * 2;
#pragma unroll
    for (int k = 0; k < 8; ++k) {
        const int c = r8 + k * 8;
        floatx2 v = *(const floatx2*)(x + ((long)(b * 512 + c0 + c)) * 4096 + n0 + col2);
        unsigned int pk = (unsigned int)f2bf(v.x) | ((unsigned int)f2bf(v.y) << 16);
        *(unsigned int*)&T[c * 66 + col2] = pk;
    }
    __syncthreads();
#pragma unroll
    for (int k = 0; k < 8; ++k) {
        const int n = r8 + k * 8;
        unsigned int pk = (unsigned int)T[col2 * 66 + n] | ((unsigned int)T[(col2 + 1) * 66 + n] << 16);
        *(unsigned int*)(xT + ((long)(b * 4096 + n0 + n)) * 512 + c0 + col2) = pk;
    }
}

// ---------------------------------------------------------------------------
// fp32 weights -> bf16 ws (wq,wk,wv,wcq,wck,wcv,wco packed)
// ---------------------------------------------------------------------------
__global__ __launch_bounds__(256) void convert_weights(
    const float* __restrict__ s0, const float* __restrict__ s1, const float* __restrict__ s2,
    const float* __restrict__ s3, const float* __restrict__ s4, const float* __restrict__ s5,
    const float* __restrict__ s6, unsigned short* __restrict__ dst)
{
    const int total = 458752;
    for (int i = blockIdx.x * 256 + threadIdx.x; i < total; i += gridDim.x * 256) {
        float v; int j = i;
        if (j < 32768) v = s0[j];
        else if ((j -= 32768) < 32768) v = s1[j];
        else if ((j -= 32768) < 262144) v = s2[j];
        else if ((j -= 262144) < 32768) v = s3[j];
        else if ((j -= 32768) < 32768) v = s4[j];
        else if ((j -= 32768) < 32768) v = s5[j];
        else v = s6[j - 32768];
        dst[i] = f2bf(v);
    }
}

// ---------------------------------------------------------------------------
// channel softmax over q (64 logits, fp32) -> c_attn bf16
// ---------------------------------------------------------------------------
__global__ __launch_bounds__(64) void chan_softmax(
    const float* __restrict__ ce, unsigned short* __restrict__ ca)
{
    const int p = blockIdx.x, b = blockIdx.y, q = threadIdx.x;
    const long base = ((long)b * 64 + p) * 64;
    float v = ce[base + q];
    float m = v;
#pragma unroll
    for (int s = 32; s >= 1; s >>= 1) m = fmaxf(m, __shfl_xor(m, s));
    float e = exp2f((v - m) * LOG2E);
    float sum = e;
#pragma unroll
    for (int s = 32; s >= 1; s >>= 1) sum += __shfl_xor(sum, s);
    ca[base + q] = f2bf(e / sum);
}

// ---------------------------------------------------------------------------
extern "C" void kernel_launch(void* const* d_in, const int* in_sizes, int n_in,
                              void* d_out, int out_size, void* d_ws, size_t ws_size,
                              hipStream_t stream) {
    const float* x    = (const float*)d_in[0];
    const float* pq_w = (const float*)d_in[1];
    const float* pq_b = (const float*)d_in[2];
    const float* pk_w = (const float*)d_in[3];
    const float* pk_b = (const float*)d_in[4];
    const float* pv_w = (const float*)d_in[5];
    const float* pv_b = (const float*)d_in[6];
    const float* cq_w = (const float*)d_in[7];
    const float* cq_b = (const float*)d_in[8];
    const float* ck_w = (const float*)d_in[9];
    const float* ck_b = (const float*)d_in[10];
    const float* cv_w = (const float*)d_in[11];
    const float* cv_b = (const float*)d_in[12];
    const float* co_w = (const float*)d_in[13];
    const float* co_b = (const float*)d_in[14];
    float* out = (float*)d_out;
    char* ws = (char*)d_ws;

    // ws layout (bytes)
    constexpr long OFF_XT    = 0;                       // bf16 [8][4096][512]
    constexpr long OFF_QT    = 33554432;                // bf16 [8][4096][64]
    constexpr long OFF_KT    = OFF_QT + 4194304;
    constexpr long OFF_VP    = OFF_KT + 4194304;        // bf16 [8][512][4096] (v * rcp_l)
    constexpr long OFF_CQ    = OFF_VP + 33554432;       // bf16 [8][64][4096]
    constexpr long OFF_CK    = OFF_CQ + 4194304;
    constexpr long OFF_CVT   = OFF_CK + 4194304;        // bf16 [8][4096][64]
    constexpr long OFF_COT   = OFF_CVT + 4194304;       // bf16 [8][4096][64]
    constexpr long OFF_RCL   = OFF_COT + 4194304;       // fp32 [8][4096]
    constexpr long OFF_CE    = OFF_RCL + 131072;        // fp32 [8][64][64]
    constexpr long OFF_CATTN = OFF_CE + 131072;         // bf16 [8][64][64]
    constexpr long OFF_WB    = OFF_CATTN + 65536;       // bf16 weights (458752 elems)

    unsigned short* xT  = (unsigned short*)(ws + OFF_XT);
    unsigned short* qT  = (unsigned short*)(ws + OFF_QT);
    unsigned short* kT  = (unsigned short*)(ws + OFF_KT);
    unsigned short* vP  = (unsigned short*)(ws + OFF_VP);
    unsigned short* cq  = (unsigned short*)(ws + OFF_CQ);
    unsigned short* ck  = (unsigned short*)(ws + OFF_CK);
    unsigned short* cvT = (unsigned short*)(ws + OFF_CVT);
    unsigned short* coT = (unsigned short*)(ws + OFF_COT);
    float*          rcl = (float*)(ws + OFF_RCL);
    float*          ce  = (float*)(ws + OFF_CE);
    unsigned short* cat = (unsigned short*)(ws + OFF_CATTN);
    unsigned short* wb  = (unsigned short*)(ws + OFF_WB);
    unsigned short* wq  = wb;
    unsigned short* wk  = wb + 32768;
    unsigned short* wv  = wb + 65536;
    unsigned short* wcq = wb + 327680;
    unsigned short* wck = wb + 360448;
    unsigned short* wcv = wb + 393216;
    unsigned short* wco = wb + 425984;

    // 0) convert weights, transpose x
    convert_weights<<<dim3(64), 256, 0, stream>>>(pq_w, pk_w, pv_w, cq_w, ck_w, cv_w, co_w, wb);
    transpose_x<<<dim3(64, 8, 8), 256, 0, stream>>>(x, xT);

    // 1) projections (TN GEMMs). qT/kT/cvT: [4096,64] (bias on n); cq/ck: [64,4096] (bias on m)
    tn_gemm<128, 64, true, false><<<dim3(1, 32, 8), 256, 0, stream>>>(
        xT, 512, 2097152L, wq, 512, 0L, qT, 64, 262144L, nullptr, pq_b, nullptr, 0L, 512, 1);
    tn_gemm<128, 64, true, false><<<dim3(1, 32, 8), 256, 0, stream>>>(
        xT, 512, 2097152L, wk, 512, 0L, kT, 64, 262144L, nullptr, pk_b, nullptr, 0L, 512, 1);
    tn_gemm<64, 128, true, false><<<dim3(32, 1, 8), 256, 0, stream>>>(
        wcq, 512, 0L, xT, 512, 2097152L, cq, 4096, 262144L, cq_b, nullptr, nullptr, 0L, 512, 1);
    tn_gemm<64, 128, true, false><<<dim3(32, 1, 8), 256, 0, stream>>>(
        wck, 512, 0L, xT, 512, 2097152L, ck, 4096, 262144L, ck_b, nullptr, nullptr, 0L, 512, 1);
    tn_gemm<128, 64, true, false><<<dim3(1, 32, 8), 256, 0, stream>>>(
        xT, 512, 2097152L, wcv, 512, 0L, cvT, 64, 262144L, nullptr, cv_b, nullptr, 0L, 512, 1);

    // 2) softmax denominators -> rcp_l
    rowsum_kernel<<<dim3(32, 1, 8), 256, 0, stream>>>(qT, kT, rcl);

    // 3) v' = (Wv x + b) * rcp_l  (column scale by position)
    tn_gemm<128, 128, true, false><<<dim3(32, 4, 8), 256, 0, stream>>>(
        wv, 512, 0L, xT, 512, 2097152L, vP, 4096, 2097152L, pv_b, nullptr, rcl, 4096L, 512, 1);

    // 4) channel attention: c_energy (split-K atomic), softmax, c_outT, chan_out -> d_out
    hipMemsetAsync(ce, 0, 8 * 64 * 64 * sizeof(float), stream);
    tn_gemm<64, 64, false, true><<<dim3(1, 1, 64), 256, 0, stream>>>(
        cq, 4096, 262144L, ck, 4096, 262144L, ce, 64, 4096L, nullptr, nullptr, nullptr, 0L, 512, 8);
    chan_softmax<<<dim3(64, 8), 64, 0, stream>>>(ce, cat);
    tn_gemm<128, 64, true, false><<<dim3(1, 32, 8), 256, 0, stream>>>(
        cvT, 64, 262144L, cat, 64, 4096L, coT, 64, 262144L, nullptr, nullptr, nullptr, 0L, 64, 1);
    tn_gemm<128, 128, false, false><<<dim3(32, 4, 8), 256, 0, stream>>>(
        wco, 64, 0L, coT, 64, 262144L, out, 4096, 2097152L, co_b, nullptr, nullptr, 0L, 64, 1);

    // 5) fused position attention, accumulates into d_out
    pos_attn_kernel<<<dim3(32, 4, 8), 256, 0, stream>>>(qT, kT, vP, out);
}

// Round 2
// 773.420 us; speedup vs baseline: 1.0537x; 1.0537x over previous
//
#include <hip/hip_runtime.h>
#include <stdint.h>

// ---------------------------------------------------------------------------
// Dual attention (DANet): pos attention + channel attention, fused pipeline.
// B=8, C=512, CQ=64, H=W=64, HW=4096.  All GEMMs bf16 MFMA 16x16x32, fp32 acc.
//
// pos_out[c,j] = sum_i v'[c,i] * exp(e[i,j]),  v' = (Wv x + b) * rcp_l[i],
//   rcp_l[i] = 1 / sum_j exp(e[i,j])   (no max subtraction: |e| <~ 13)
// qT is pre-scaled by LOG2E so exp(e) == exp2(e'), saving a mul per element.
// pos_attn: c-tile=512 (full), j-tile=64 -> E/exp computed exactly once.
// chan_out (K=64 GEMM) fused into pos_attn epilogue -> out written once.
// ---------------------------------------------------------------------------

#define LOG2E 1.44269504088896340736f

typedef __attribute__((ext_vector_type(8))) __bf16 bf16x8;
typedef __attribute__((ext_vector_type(4))) float floatx4;
typedef __attribute__((ext_vector_type(2))) float floatx2;
typedef __attribute__((ext_vector_type(2))) unsigned int uint2v;

static __device__ __forceinline__ unsigned short f2bf(float f) {
    union { float f; uint32_t u; } v; v.f = f;
    uint32_t r = v.u + 0x7fffu + ((v.u >> 16) & 1u);   // RNE
    return (unsigned short)(r >> 16);
}

// pack two fp32 -> bf16x2 (round-half-up: +0x8000 then take high16 via v_perm)
static __device__ __forceinline__ unsigned int pack_bf16(float a, float b) {
    union { float f; uint32_t u; } x, y; x.f = a; y.f = b;
    return __builtin_amdgcn_perm(y.u + 0x8000u, x.u + 0x8000u, 0x07060302u);
}

// ---------------------------------------------------------------------------
// Generic TN GEMM: C[m,n] = (sum_k A[m,k]*B[n,k] + bias_m[m] + bias_n[n])
//                  * scale_n[n] * cscale.   A,B bf16 K-contiguous. BK=64.
// ---------------------------------------------------------------------------
template<int BM, int BN, bool OUT_BF16, bool ATOMIC>
__global__ __launch_bounds__(256) void tn_gemm(
    const unsigned short* __restrict__ A, int lda, long sA,
    const unsigned short* __restrict__ B, int ldb, long sB,
    void* __restrict__ C, int ldc, long sC,
    const float* __restrict__ bias_m, const float* __restrict__ bias_n,
    const float* __restrict__ scale_n, long sScale, float cscale,
    int K, int kchunks)
{
    constexpr int PK = 72;                 // 64 + 8 pad
    __shared__ unsigned short As[BM * PK];
    __shared__ unsigned short Bs[BN * PK];
    const int bz = blockIdx.z;
    const int b  = bz / kchunks;
    const int kc = bz % kchunks;
    const int m0 = blockIdx.y * BM;
    const int n0 = blockIdx.x * BN;
    const unsigned short* Ab = A + (long)b * sA + (long)m0 * lda + (long)kc * K;
    const unsigned short* Bb = B + (long)b * sB + (long)n0 * ldb + (long)kc * K;
    const int tid = threadIdx.x;
    const int lane = tid & 63, wave = tid >> 6;
    const int l15 = lane & 15, quad = lane >> 4;
    constexpr int NT  = BN / 16;
    constexpr int MPW = BM / 64;
    constexpr int AL  = BM / 32;
    constexpr int BL  = BN / 32;

    const floatx4 vz = {0.f, 0.f, 0.f, 0.f};
    floatx4 acc[MPW][NT];
    for (int i = 0; i < MPW; ++i) for (int j = 0; j < NT; ++j) acc[i][j] = vz;

    const int nK = K >> 6;
    for (int k0 = 0; k0 < nK; ++k0) {
        floatx4 ar[AL], br[BL];
#pragma unroll
        for (int L = 0; L < AL; ++L) {
            int flat = L * 2048 + tid * 8;
            ar[L] = *(const floatx4*)(Ab + (long)(flat >> 6) * lda + (k0 << 6) + (flat & 63));
        }
#pragma unroll
        for (int L = 0; L < BL; ++L) {
            int flat = L * 2048 + tid * 8;
            br[L] = *(const floatx4*)(Bb + (long)(flat >> 6) * ldb + (k0 << 6) + (flat & 63));
        }
        __syncthreads();
#pragma unroll
        for (int L = 0; L < AL; ++L) {
            int flat = L * 2048 + tid * 8;
            *(floatx4*)&As[(flat >> 6) * PK + (flat & 63)] = ar[L];
        }
#pragma unroll
        for (int L = 0; L < BL; ++L) {
            int flat = L * 2048 + tid * 8;
            *(floatx4*)&Bs[(flat >> 6) * PK + (flat & 63)] = br[L];
        }
        __syncthreads();
#pragma unroll
        for (int ks = 0; ks < 2; ++ks) {
            bf16x8 af[MPW];
#pragma unroll
            for (int mi = 0; mi < MPW; ++mi)
                af[mi] = *(const bf16x8*)&As[((wave * MPW + mi) * 16 + l15) * PK + ks * 32 + quad * 8];
#pragma unroll
            for (int nt = 0; nt < NT; ++nt) {
                bf16x8 bf = *(const bf16x8*)&Bs[(nt * 16 + l15) * PK + ks * 32 + quad * 8];
#pragma unroll
                for (int mi = 0; mi < MPW; ++mi)
                    acc[mi][nt] = __builtin_amdgcn_mfma_f32_16x16x32_bf16(af[mi], bf, acc[mi][nt], 0, 0, 0);
            }
        }
    }
    // epilogue (C/D layout: col = lane&15, row = quad*4 + r)
#pragma unroll
    for (int mi = 0; mi < MPW; ++mi) {
        const int mb = m0 + (wave * MPW + mi) * 16 + quad * 4;
#pragma unroll
        for (int nt = 0; nt < NT; ++nt) {
            const int n = n0 + nt * 16 + l15;
            const float bn = bias_n ? bias_n[n] : 0.f;
            const float cs = (scale_n ? scale_n[(long)b * sScale + n] : 1.f) * cscale;
            floatx4 a = acc[mi][nt];
#pragma unroll
            for (int r = 0; r < 4; ++r) {
                const int m = mb + r;
                float v = (a[r] + (bias_m ? bias_m[m] : 0.f) + bn) * cs;
                const long idx = (long)b * sC + (long)m * ldc + n;
                if (ATOMIC)         atomicAdd((float*)C + idx, v);
                else if (OUT_BF16)  ((unsigned short*)C)[idx] = f2bf(v);
                else                ((float*)C)[idx] = v;
            }
        }
    }
}

// ---------------------------------------------------------------------------
// rcp_l[b,i] = 1 / sum_j exp2(E'[i,j]) (qT pre-scaled by LOG2E).
// grid (b, itile) so block->XCD ~ batch: kT slice stays L2-resident.
// ---------------------------------------------------------------------------
__global__ __launch_bounds__(256) void rowsum_kernel(
    const unsigned short* __restrict__ qT, const unsigned short* __restrict__ kT,
    float* __restrict__ rcl)
{
    __shared__ unsigned short Qs[128 * 72];
    const int b  = blockIdx.x;
    const int i0 = blockIdx.y * 128;
    const unsigned short* qb = qT + ((long)b * 4096 + i0) * 64;
    const unsigned short* kb = kT + (long)b * 4096 * 64;
    const int tid = threadIdx.x, lane = tid & 63, wave = tid >> 6;
    const int l15 = lane & 15, quad = lane >> 4;
#pragma unroll
    for (int L = 0; L < 4; ++L) {
        int flat = L * 2048 + tid * 8;
        *(floatx4*)&Qs[(flat >> 6) * 72 + (flat & 63)] =
            *(const floatx4*)(qb + (long)(flat >> 6) * 64 + (flat & 63));
    }
    __syncthreads();
    bf16x8 af[2][2];
#pragma unroll
    for (int mi = 0; mi < 2; ++mi)
#pragma unroll
        for (int ks = 0; ks < 2; ++ks)
            af[mi][ks] = *(const bf16x8*)&Qs[((wave * 2 + mi) * 16 + l15) * 72 + ks * 32 + quad * 8];

    float rs[2][4];
    for (int mi = 0; mi < 2; ++mi) for (int r = 0; r < 4; ++r) rs[mi][r] = 0.f;
    const floatx4 vz = {0.f, 0.f, 0.f, 0.f};
    for (int jb = 0; jb < 32; ++jb) {
        const unsigned short* kblk = kb + (long)jb * 128 * 64;
        floatx4 e[2][8];
        for (int mi = 0; mi < 2; ++mi) for (int nt = 0; nt < 8; ++nt) e[mi][nt] = vz;
#pragma unroll
        for (int ks = 0; ks < 2; ++ks)
#pragma unroll
            for (int nt = 0; nt < 8; ++nt) {
                bf16x8 bf = *(const bf16x8*)(kblk + (long)((nt * 16 + l15) * 64) + ks * 32 + quad * 8);
#pragma unroll
                for (int mi = 0; mi < 2; ++mi)
                    e[mi][nt] = __builtin_amdgcn_mfma_f32_16x16x32_bf16(af[mi][ks], bf, e[mi][nt], 0, 0, 0);
            }
#pragma unroll
        for (int mi = 0; mi < 2; ++mi)
#pragma unroll
            for (int nt = 0; nt < 8; ++nt)
#pragma unroll
                for (int r = 0; r < 4; ++r)
                    rs[mi][r] += exp2f(e[mi][nt][r]);
    }
#pragma unroll
    for (int mi = 0; mi < 2; ++mi)
#pragma unroll
        for (int r = 0; r < 4; ++r) {
            float v = rs[mi][r];
            v += __shfl_xor(v, 1); v += __shfl_xor(v, 2);
            v += __shfl_xor(v, 4); v += __shfl_xor(v, 8);
            if (l15 == 0)
                rcl[(long)b * 4096 + i0 + (wave * 2 + mi) * 16 + quad * 4 + r] = 1.0f / v;
        }
}

// ---------------------------------------------------------------------------
// Fused position attention + channel-output epilogue.
// Block = (batch, j-tile 64); c-tile = full 512 -> E/exp computed ONCE.
// Per i-iter (128): E = Q'K^T (MFMA, K=64) -> exp2 -> bf16 P^T in LDS ->
// out_acc += V' P (MFMA, K=128). Epilogue adds wco . coT^T (K=64) + co_b,
// writes out once (no RMW).  grid.x = batch -> per-XCD L2 holds that batch's
// vP (4MB) / qT / kT / coT.
// ---------------------------------------------------------------------------
__global__ __launch_bounds__(256) void pos_attn_kernel(
    const unsigned short* __restrict__ qT, const unsigned short* __restrict__ kT,
    const unsigned short* __restrict__ vP, const unsigned short* __restrict__ wco,
    const unsigned short* __restrict__ coT, const float* __restrict__ co_b,
    float* __restrict__ out)
{
    __shared__ unsigned short Ks[64 * 72];     // j 64 x k 64 (+8 pad)
    __shared__ unsigned short Ps[64 * 136];    // j 64 x i 128 (+8 pad)
    const int b  = blockIdx.x;
    const int j0 = blockIdx.y * 64;
    const unsigned short* qb = qT + (long)b * 4096 * 64;
    const unsigned short* kb = kT + ((long)b * 4096 + j0) * 64;
    const unsigned short* vb = vP + (long)b * 512 * 4096;
    const int tid = threadIdx.x, lane = tid & 63, wave = tid >> 6;
    const int l15 = lane & 15, quad = lane >> 4;
#pragma unroll
    for (int L = 0; L < 2; ++L) {
        int flat = L * 2048 + tid * 8;
        *(floatx4*)&Ks[(flat >> 6) * 72 + (flat & 63)] =
            *(const floatx4*)(kb + (long)(flat >> 6) * 64 + (flat & 63));
    }
    const floatx4 vz = {0.f, 0.f, 0.f, 0.f};
    floatx4 oacc[8][4];
#pragma unroll
    for (int mi = 0; mi < 8; ++mi) for (int nt = 0; nt < 4; ++nt) oacc[mi][nt] = vz;
    __syncthreads();

    for (int ib = 0; ib < 32; ++ib) {
        const unsigned short* qblk = qb + (long)ib * 128 * 64;
        // --- E' = Q' K^T block (m=i 128, n=j 64, k=64); wave owns 32 i-rows ---
        floatx4 e[2][4];
        for (int mi = 0; mi < 2; ++mi) for (int nt = 0; nt < 4; ++nt) e[mi][nt] = vz;
#pragma unroll
        for (int ks = 0; ks < 2; ++ks) {
            bf16x8 af[2];
#pragma unroll
            for (int mi = 0; mi < 2; ++mi)
                af[mi] = *(const bf16x8*)(qblk + (long)(((wave * 2 + mi) * 16 + l15) * 64) + ks * 32 + quad * 8);
#pragma unroll
            for (int nt = 0; nt < 4; ++nt) {
                bf16x8 bf = *(const bf16x8*)&Ks[(nt * 16 + l15) * 72 + ks * 32 + quad * 8];
#pragma unroll
                for (int mi = 0; mi < 2; ++mi)
                    e[mi][nt] = __builtin_amdgcn_mfma_f32_16x16x32_bf16(af[mi], bf, e[mi][nt], 0, 0, 0);
            }
        }
        __syncthreads();   // previous PV done reading Ps
        // --- P^T = exp2(E') -> bf16 LDS (pack pairs via v_perm) ---
#pragma unroll
        for (int mi = 0; mi < 2; ++mi) {
            const int il = (wave * 2 + mi) * 16 + quad * 4;
#pragma unroll
            for (int nt = 0; nt < 4; ++nt) {
                uint2v p;
                p.x = pack_bf16(exp2f(e[mi][nt][0]), exp2f(e[mi][nt][1]));
                p.y = pack_bf16(exp2f(e[mi][nt][2]), exp2f(e[mi][nt][3]));
                *(uint2v*)&Ps[(nt * 16 + l15) * 136 + il] = p;
            }
        }
        __syncthreads();
        // --- out += V' * P (m=c 512, n=j 64, k=i 128); wave owns 128 c-rows ---
#pragma unroll
        for (int ks = 0; ks < 4; ++ks) {
            bf16x8 af[8];
#pragma unroll
            for (int mi = 0; mi < 8; ++mi)
                af[mi] = *(const bf16x8*)(vb + (long)((wave * 8 + mi) * 16 + l15) * 4096 + ib * 128 + ks * 32 + quad * 8);
#pragma unroll
            for (int nt = 0; nt < 4; ++nt) {
                bf16x8 bf = *(const bf16x8*)&Ps[(nt * 16 + l15) * 136 + ks * 32 + quad * 8];
#pragma unroll
                for (int mi = 0; mi < 8; ++mi)
                    oacc[mi][nt] = __builtin_amdgcn_mfma_f32_16x16x32_bf16(af[mi], bf, oacc[mi][nt], 0, 0, 0);
            }
        }
    }

    // --- fused channel output: out += wco . coT^T (m=c, n=j, k=q 64) ---
#pragma unroll
    for (int ks = 0; ks < 2; ++ks) {
        bf16x8 aw[8];
#pragma unroll
        for (int mi = 0; mi < 8; ++mi)
            aw[mi] = *(const bf16x8*)(wco + (long)((wave * 8 + mi) * 16 + l15) * 64 + ks * 32 + quad * 8);
#pragma unroll
        for (int nt = 0; nt < 4; ++nt) {
            bf16x8 bf = *(const bf16x8*)(coT + ((long)b * 4096 + j0 + nt * 16 + l15) * 64 + ks * 32 + quad * 8);
#pragma unroll
            for (int mi = 0; mi < 8; ++mi)
                oacc[mi][nt] = __builtin_amdgcn_mfma_f32_16x16x32_bf16(aw[mi], bf, oacc[mi][nt], 0, 0, 0);
        }
    }
    // --- store (single write of out) ---
#pragma unroll
    for (int mi = 0; mi < 8; ++mi) {
        const int c = (wave * 8 + mi) * 16 + quad * 4;
#pragma unroll
        for (int nt = 0; nt < 4; ++nt) {
            const int j = j0 + nt * 16 + l15;
#pragma unroll
            for (int r = 0; r < 4; ++r)
                out[((long)b * 512 + c + r) * 4096 + j] = oacc[mi][nt][r] + co_b[c + r];
        }
    }
}

// ---------------------------------------------------------------------------
// x [B,512,4096] fp32 -> xT [B,4096,512] bf16 (64x64 LDS tile transpose)
// ---------------------------------------------------------------------------
__global__ __launch_bounds__(256) void transpose_x(
    const float* __restrict__ x, unsigned short* __restrict__ xT)
{
    __shared__ unsigned short T[64 * 66];
    const int b  = blockIdx.z;
    const int n0 = blockIdx.x * 64;
    const int c0 = blockIdx.y * 64;
    const int tid = threadIdx.x;
    const int r8 = tid >> 5;
    const int col2 = (tid & 31) * 2;
#pragma unroll
    for (int k = 0; k < 8; ++k) {
        const int c = r8 + k * 8;
        floatx2 v = *(const floatx2*)(x + ((long)(b * 512 + c0 + c)) * 4096 + n0 + col2);
        unsigned int pk = (unsigned int)f2bf(v.x) | ((unsigned int)f2bf(v.y) << 16);
        *(unsigned int*)&T[c * 66 + col2] = pk;
    }
    __syncthreads();
#pragma unroll
    for (int k = 0; k < 8; ++k) {
        const int n = r8 + k * 8;
        unsigned int pk = (unsigned int)T[col2 * 66 + n] | ((unsigned int)T[(col2 + 1) * 66 + n] << 16);
        *(unsigned int*)(xT + ((long)(b * 4096 + n0 + n)) * 512 + c0 + col2) = pk;
    }
}

// ---------------------------------------------------------------------------
// fp32 weights -> bf16 ws (wq,wk,wv,wcq,wck,wcv,wco packed)
// ---------------------------------------------------------------------------
__global__ __launch_bounds__(256) void convert_weights(
    const float* __restrict__ s0, const float* __restrict__ s1, const float* __restrict__ s2,
    const float* __restrict__ s3, const float* __restrict__ s4, const float* __restrict__ s5,
    const float* __restrict__ s6, unsigned short* __restrict__ dst)
{
    const int total = 458752;
    for (int i = blockIdx.x * 256 + threadIdx.x; i < total; i += gridDim.x * 256) {
        float v; int j = i;
        if (j < 32768) v = s0[j];
        else if ((j -= 32768) < 32768) v = s1[j];
        else if ((j -= 32768) < 262144) v = s2[j];
        else if ((j -= 262144) < 32768) v = s3[j];
        else if ((j -= 32768) < 32768) v = s4[j];
        else if ((j -= 32768) < 32768) v = s5[j];
        else v = s6[j - 32768];
        dst[i] = f2bf(v);
    }
}

// ---------------------------------------------------------------------------
// channel softmax over q (64 logits, fp32) -> c_attn bf16
// ---------------------------------------------------------------------------
__global__ __launch_bounds__(64) void chan_softmax(
    const float* __restrict__ ce, unsigned short* __restrict__ ca)
{
    const int p = blockIdx.x, b = blockIdx.y, q = threadIdx.x;
    const long base = ((long)b * 64 + p) * 64;
    float v = ce[base + q];
    float m = v;
#pragma unroll
    for (int s = 32; s >= 1; s >>= 1) m = fmaxf(m, __shfl_xor(m, s));
    float e = exp2f((v - m) * LOG2E);
    float sum = e;
#pragma unroll
    for (int s = 32; s >= 1; s >>= 1) sum += __shfl_xor(sum, s);
    ca[base + q] = f2bf(e / sum);
}

// ---------------------------------------------------------------------------
extern "C" void kernel_launch(void* const* d_in, const int* in_sizes, int n_in,
                              void* d_out, int out_size, void* d_ws, size_t ws_size,
                              hipStream_t stream) {
    const float* x    = (const float*)d_in[0];
    const float* pq_b = (const float*)d_in[2];
    const float* pk_b = (const float*)d_in[4];
    const float* pv_b = (const float*)d_in[6];
    const float* cq_b = (const float*)d_in[8];
    const float* ck_b = (const float*)d_in[10];
    const float* cv_b = (const float*)d_in[12];
    const float* co_b = (const float*)d_in[14];
    float* out = (float*)d_out;
    char* ws = (char*)d_ws;

    // ws layout (bytes)
    constexpr long OFF_XT    = 0;                       // bf16 [8][4096][512]
    constexpr long OFF_QT    = 33554432;                // bf16 [8][4096][64] (x LOG2E)
    constexpr long OFF_KT    = OFF_QT + 4194304;
    constexpr long OFF_VP    = OFF_KT + 4194304;        // bf16 [8][512][4096] (v * rcp_l)
    constexpr long OFF_CQ    = OFF_VP + 33554432;       // bf16 [8][64][4096]
    constexpr long OFF_CK    = OFF_CQ + 4194304;
    constexpr long OFF_CVT   = OFF_CK + 4194304;        // bf16 [8][4096][64]
    constexpr long OFF_COT   = OFF_CVT + 4194304;       // bf16 [8][4096][64]
    constexpr long OFF_RCL   = OFF_COT + 4194304;       // fp32 [8][4096]
    constexpr long OFF_CE    = OFF_RCL + 131072;        // fp32 [8][64][64]
    constexpr long OFF_CATTN = OFF_CE + 131072;         // bf16 [8][64][64]
    constexpr long OFF_WB    = OFF_CATTN + 65536;       // bf16 weights (458752 elems)

    unsigned short* xT  = (unsigned short*)(ws + OFF_XT);
    unsigned short* qT  = (unsigned short*)(ws + OFF_QT);
    unsigned short* kT  = (unsigned short*)(ws + OFF_KT);
    unsigned short* vP  = (unsigned short*)(ws + OFF_VP);
    unsigned short* cq  = (unsigned short*)(ws + OFF_CQ);
    unsigned short* ck  = (unsigned short*)(ws + OFF_CK);
    unsigned short* cvT = (unsigned short*)(ws + OFF_CVT);
    unsigned short* coT = (unsigned short*)(ws + OFF_COT);
    float*          rcl = (float*)(ws + OFF_RCL);
    float*          ce  = (float*)(ws + OFF_CE);
    unsigned short* cat = (unsigned short*)(ws + OFF_CATTN);
    unsigned short* wb  = (unsigned short*)(ws + OFF_WB);
    unsigned short* wq  = wb;
    unsigned short* wk  = wb + 32768;
    unsigned short* wv  = wb + 65536;
    unsigned short* wcq = wb + 327680;
    unsigned short* wck = wb + 360448;
    unsigned short* wcv = wb + 393216;
    unsigned short* wco = wb + 425984;

    // 0) convert weights, transpose x
    convert_weights<<<dim3(64), 256, 0, stream>>>(
        (const float*)d_in[1], (const float*)d_in[3], (const float*)d_in[5],
        (const float*)d_in[7], (const float*)d_in[9], (const float*)d_in[11],
        (const float*)d_in[13], wb);
    transpose_x<<<dim3(64, 8, 8), 256, 0, stream>>>(x, xT);

    // 1) projections. qT gets LOG2E folded in (so E' = E*log2e, exp2 direct)
    tn_gemm<128, 64, true, false><<<dim3(1, 32, 8), 256, 0, stream>>>(
        xT, 512, 2097152L, wq, 512, 0L, qT, 64, 262144L, nullptr, pq_b, nullptr, 0L, LOG2E, 512, 1);
    tn_gemm<128, 64, true, false><<<dim3(1, 32, 8), 256, 0, stream>>>(
        xT, 512, 2097152L, wk, 512, 0L, kT, 64, 262144L, nullptr, pk_b, nullptr, 0L, 1.0f, 512, 1);
    tn_gemm<64, 128, true, false><<<dim3(32, 1, 8), 256, 0, stream>>>(
        wcq, 512, 0L, xT, 512, 2097152L, cq, 4096, 262144L, cq_b, nullptr, nullptr, 0L, 1.0f, 512, 1);
    tn_gemm<64, 128, true, false><<<dim3(32, 1, 8), 256, 0, stream>>>(
        wck, 512, 0L, xT, 512, 2097152L, ck, 4096, 262144L, ck_b, nullptr, nullptr, 0L, 1.0f, 512, 1);
    tn_gemm<128, 64, true, false><<<dim3(1, 32, 8), 256, 0, stream>>>(
        xT, 512, 2097152L, wcv, 512, 0L, cvT, 64, 262144L, nullptr, cv_b, nullptr, 0L, 1.0f, 512, 1);

    // 2) softmax denominators -> rcp_l
    rowsum_kernel<<<dim3(8, 32), 256, 0, stream>>>(qT, kT, rcl);

    // 3) v' = (Wv x + b) * rcp_l  (column scale by position)
    tn_gemm<128, 128, true, false><<<dim3(32, 4, 8), 256, 0, stream>>>(
        wv, 512, 0L, xT, 512, 2097152L, vP, 4096, 2097152L, pv_b, nullptr, rcl, 4096L, 1.0f, 512, 1);

    // 4) channel attention: c_energy (split-K atomic), softmax, c_outT
    hipMemsetAsync(ce, 0, 8 * 64 * 64 * sizeof(float), stream);
    tn_gemm<64, 64, false, true><<<dim3(1, 1, 64), 256, 0, stream>>>(
        cq, 4096, 262144L, ck, 4096, 262144L, ce, 64, 4096L, nullptr, nullptr, nullptr, 0L, 1.0f, 512, 8);
    chan_softmax<<<dim3(64, 8), 64, 0, stream>>>(ce, cat);
    tn_gemm<128, 64, true, false><<<dim3(1, 32, 8), 256, 0, stream>>>(
        cvT, 64, 262144L, cat, 64, 4096L, coT, 64, 262144L, nullptr, nullptr, nullptr, 0L, 1.0f, 64, 1);

    // 5) fused position attention + channel output epilogue -> out (1 write)
    pos_attn_kernel<<<dim3(8, 64), 256, 0, stream>>>(qT, kT, vP, wco, coT, co_b, out);
}

// Round 3
// 596.809 us; speedup vs baseline: 1.3656x; 1.2959x over previous
//
#include <hip/hip_runtime.h>
#include <stdint.h>

// ---------------------------------------------------------------------------
// Dual attention (DANet): pos attention + channel attention, fused pipeline.
// B=8, C=512, CQ=64, H=W=64, HW=4096.  All GEMMs bf16 MFMA 16x16x32, fp32 acc.
//
// pos_out[c,j] = sum_i v'[c,i] * exp(e[i,j]),  v' = (Wv x + b) * rcp_l[i],
//   rcp_l[i] = 1 / sum_j exp(e[i,j])   (no max subtraction: |e| <~ 13)
// LOG2E folded into wq/pq_b at convert time -> exp2 direct.
// q,k,cv fused into one [192,512] projection GEMM; cq,ck into one [128,512].
// pos_attn: 8-wave blocks, c-tile=512, j-tile=64, double-buffered P^T in LDS,
// ONE barrier per i-iter; chan_out GEMM fused into epilogue (out written once).
// ---------------------------------------------------------------------------

#define LOG2E 1.44269504088896340736f

typedef __attribute__((ext_vector_type(8))) __bf16 bf16x8;
typedef __attribute__((ext_vector_type(4))) float floatx4;
typedef __attribute__((ext_vector_type(2))) float floatx2;
typedef __attribute__((ext_vector_type(2))) unsigned int uint2v;

static __device__ __forceinline__ unsigned short f2bf(float f) {
    union { float f; uint32_t u; } v; v.f = f;
    uint32_t r = v.u + 0x7fffu + ((v.u >> 16) & 1u);   // RNE
    return (unsigned short)(r >> 16);
}

// pack two fp32 -> bf16x2 (round-half-up: +0x8000, take high16 via v_perm)
static __device__ __forceinline__ unsigned int pack_bf16(float a, float b) {
    union { float f; uint32_t u; } x, y; x.f = a; y.f = b;
    return __builtin_amdgcn_perm(y.u + 0x8000u, x.u + 0x8000u, 0x07060302u);
}

// ---------------------------------------------------------------------------
// Generic TN GEMM: C[m,n] = (sum_k A[m,k]*B[n,k] + bias_m[m] + bias_n[n])
//                  * scale_n[n].   A,B bf16 K-contiguous. BK=64.
// ---------------------------------------------------------------------------
template<int BM, int BN, bool OUT_BF16, bool ATOMIC>
__global__ __launch_bounds__(256) void tn_gemm(
    const unsigned short* __restrict__ A, int lda, long sA,
    const unsigned short* __restrict__ B, int ldb, long sB,
    void* __restrict__ C, int ldc, long sC,
    const float* __restrict__ bias_m, const float* __restrict__ bias_n,
    const float* __restrict__ scale_n, long sScale,
    int K, int kchunks)
{
    constexpr int PK = 72;                 // 64 + 8 pad
    __shared__ unsigned short As[BM * PK];
    __shared__ unsigned short Bs[BN * PK];
    const int bz = blockIdx.z;
    const int b  = bz / kchunks;
    const int kc = bz % kchunks;
    const int m0 = blockIdx.y * BM;
    const int n0 = blockIdx.x * BN;
    const unsigned short* Ab = A + (long)b * sA + (long)m0 * lda + (long)kc * K;
    const unsigned short* Bb = B + (long)b * sB + (long)n0 * ldb + (long)kc * K;
    const int tid = threadIdx.x;
    const int lane = tid & 63, wave = tid >> 6;
    const int l15 = lane & 15, quad = lane >> 4;
    constexpr int NT  = BN / 16;
    constexpr int MPW = BM / 64;
    constexpr int AL  = BM / 32;
    constexpr int BL  = BN / 32;

    const floatx4 vz = {0.f, 0.f, 0.f, 0.f};
    floatx4 acc[MPW][NT];
    for (int i = 0; i < MPW; ++i) for (int j = 0; j < NT; ++j) acc[i][j] = vz;

    const int nK = K >> 6;
    for (int k0 = 0; k0 < nK; ++k0) {
        floatx4 ar[AL], br[BL];
#pragma unroll
        for (int L = 0; L < AL; ++L) {
            int flat = L * 2048 + tid * 8;
            ar[L] = *(const floatx4*)(Ab + (long)(flat >> 6) * lda + (k0 << 6) + (flat & 63));
        }
#pragma unroll
        for (int L = 0; L < BL; ++L) {
            int flat = L * 2048 + tid * 8;
            br[L] = *(const floatx4*)(Bb + (long)(flat >> 6) * ldb + (k0 << 6) + (flat & 63));
        }
        __syncthreads();
#pragma unroll
        for (int L = 0; L < AL; ++L) {
            int flat = L * 2048 + tid * 8;
            *(floatx4*)&As[(flat >> 6) * PK + (flat & 63)] = ar[L];
        }
#pragma unroll
        for (int L = 0; L < BL; ++L) {
            int flat = L * 2048 + tid * 8;
            *(floatx4*)&Bs[(flat >> 6) * PK + (flat & 63)] = br[L];
        }
        __syncthreads();
#pragma unroll
        for (int ks = 0; ks < 2; ++ks) {
            bf16x8 af[MPW];
#pragma unroll
            for (int mi = 0; mi < MPW; ++mi)
                af[mi] = *(const bf16x8*)&As[((wave * MPW + mi) * 16 + l15) * PK + ks * 32 + quad * 8];
#pragma unroll
            for (int nt = 0; nt < NT; ++nt) {
                bf16x8 bf = *(const bf16x8*)&Bs[(nt * 16 + l15) * PK + ks * 32 + quad * 8];
#pragma unroll
                for (int mi = 0; mi < MPW; ++mi)
                    acc[mi][nt] = __builtin_amdgcn_mfma_f32_16x16x32_bf16(af[mi], bf, acc[mi][nt], 0, 0, 0);
            }
        }
    }
    // epilogue (C/D layout: col = lane&15, row = quad*4 + r)
#pragma unroll
    for (int mi = 0; mi < MPW; ++mi) {
        const int mb = m0 + (wave * MPW + mi) * 16 + quad * 4;
#pragma unroll
        for (int nt = 0; nt < NT; ++nt) {
            const int n = n0 + nt * 16 + l15;
            const float bn = bias_n ? bias_n[n] : 0.f;
            const float cs = scale_n ? scale_n[(long)b * sScale + n] : 1.f;
            floatx4 a = acc[mi][nt];
#pragma unroll
            for (int r = 0; r < 4; ++r) {
                const int m = mb + r;
                float v = (a[r] + (bias_m ? bias_m[m] : 0.f) + bn) * cs;
                const long idx = (long)b * sC + (long)m * ldc + n;
                if (ATOMIC)         atomicAdd((float*)C + idx, v);
                else if (OUT_BF16)  ((unsigned short*)C)[idx] = f2bf(v);
                else                ((float*)C)[idx] = v;
            }
        }
    }
}

// ---------------------------------------------------------------------------
// rcp_l[b,i] = 1 / sum_j exp2(E'[i,j]).  qkvT rows: [q(0..63) k(64..127) cv],
// lda 192.  8-wave blocks, i-tile 128 (16 rows/wave, q frags in regs),
// K-tile 128 double-buffered in LDS, one barrier per tile.
// ---------------------------------------------------------------------------
__global__ __launch_bounds__(512, 4) void rowsum_kernel(
    const unsigned short* __restrict__ qkvT, float* __restrict__ rcl)
{
    __shared__ unsigned short Ks[2][128 * 72];
    const int b  = blockIdx.x;
    const int i0 = blockIdx.y * 128;
    const unsigned short* qb = qkvT + (long)b * 786432 + (long)i0 * 192;
    const unsigned short* kb = qkvT + (long)b * 786432 + 64;
    const int tid = threadIdx.x, lane = tid & 63, wave = tid >> 6;
    const int l15 = lane & 15, quad = lane >> 4;

    bf16x8 af[2];
#pragma unroll
    for (int ks = 0; ks < 2; ++ks)
        af[ks] = *(const bf16x8*)(qb + (long)(wave * 16 + l15) * 192 + ks * 32 + quad * 8);

    // stage jb=0 tile (128 rows x 64): 2 passes of 512 thr x 8
#pragma unroll
    for (int p = 0; p < 2; ++p) {
        int flat = p * 4096 + tid * 8;
        *(floatx4*)&Ks[0][(flat >> 6) * 72 + (flat & 63)] =
            *(const floatx4*)(kb + (long)(flat >> 6) * 192 + (flat & 63));
    }
    float rs[4] = {0.f, 0.f, 0.f, 0.f};
    const floatx4 vz = {0.f, 0.f, 0.f, 0.f};
    __syncthreads();

    for (int jb = 0; jb < 32; ++jb) {
        const int cur = jb & 1;
        floatx4 stage[2];
        if (jb < 31) {
#pragma unroll
            for (int p = 0; p < 2; ++p) {
                int flat = p * 4096 + tid * 8;
                stage[p] = *(const floatx4*)(kb + (long)((jb + 1) * 128 + (flat >> 6)) * 192 + (flat & 63));
            }
        }
        floatx4 e[8];
#pragma unroll
        for (int nt = 0; nt < 8; ++nt) e[nt] = vz;
#pragma unroll
        for (int ks = 0; ks < 2; ++ks)
#pragma unroll
            for (int nt = 0; nt < 8; ++nt) {
                bf16x8 bf = *(const bf16x8*)&Ks[cur][(nt * 16 + l15) * 72 + ks * 32 + quad * 8];
                e[nt] = __builtin_amdgcn_mfma_f32_16x16x32_bf16(af[ks], bf, e[nt], 0, 0, 0);
            }
#pragma unroll
        for (int nt = 0; nt < 8; ++nt)
#pragma unroll
            for (int r = 0; r < 4; ++r)
                rs[r] += exp2f(e[nt][r]);
        if (jb < 31) {
#pragma unroll
            for (int p = 0; p < 2; ++p) {
                int flat = p * 4096 + tid * 8;
                *(floatx4*)&Ks[1 - cur][(flat >> 6) * 72 + (flat & 63)] = stage[p];
            }
        }
        __syncthreads();
    }
#pragma unroll
    for (int r = 0; r < 4; ++r) {
        float v = rs[r];
        v += __shfl_xor(v, 1); v += __shfl_xor(v, 2);
        v += __shfl_xor(v, 4); v += __shfl_xor(v, 8);
        if (l15 == 0)
            rcl[(long)b * 4096 + i0 + wave * 16 + quad * 4 + r] = 1.0f / v;
    }
}

// ---------------------------------------------------------------------------
// Fused position attention + channel-output epilogue.
// Block = (batch, j-tile 64), 512 threads (8 waves); c-tile = 512 (full).
// Per i-iter (128): ONE barrier. Region: PV(ib) reads Ps[cur] || E(ib+1)
// writes Ps[1-cur].  E: each wave 16 i-rows (q frags direct global);
// PV: each wave 64 c-rows (V frags direct global, L2-shared across blocks).
// Epilogue adds wco . coT^T (K=64) + co_b, writes out once.
// ---------------------------------------------------------------------------
__global__ __launch_bounds__(512, 4) void pos_attn_kernel(
    const unsigned short* __restrict__ qkvT, const unsigned short* __restrict__ vP,
    const unsigned short* __restrict__ wco, const unsigned short* __restrict__ coT,
    const float* __restrict__ co_b, float* __restrict__ out)
{
    __shared__ unsigned short Ks[64 * 72];
    __shared__ unsigned short Ps[2][64 * 136];   // P^T [j][i 128], +8 pad
    const int b  = blockIdx.x;
    const int j0 = blockIdx.y * 64;
    const unsigned short* qb = qkvT + (long)b * 786432;
    const unsigned short* kb = qkvT + (long)b * 786432 + 64 + (long)j0 * 192;
    const unsigned short* vb = vP + (long)b * 512 * 4096;
    const int tid = threadIdx.x, lane = tid & 63, wave = tid >> 6;
    const int l15 = lane & 15, quad = lane >> 4;
    const int il = wave * 16 + quad * 4;

    // stage Ks (64 x 64 = 4096 shorts, one pass of 512 thr x 8)
    {
        int flat = tid * 8;
        *(floatx4*)&Ks[(flat >> 6) * 72 + (flat & 63)] =
            *(const floatx4*)(kb + (long)(flat >> 6) * 192 + (flat & 63));
    }
    const floatx4 vz = {0.f, 0.f, 0.f, 0.f};
    floatx4 oacc[4][4];
#pragma unroll
    for (int mi = 0; mi < 4; ++mi) for (int nt = 0; nt < 4; ++nt) oacc[mi][nt] = vz;
    __syncthreads();

    // E phase for i-block ib -> Ps[buf]
    auto e_phase = [&](int ib, int buf) {
        const unsigned short* qr = qb + (long)(ib * 128 + wave * 16 + l15) * 192;
        bf16x8 a0 = *(const bf16x8*)(qr + quad * 8);
        bf16x8 a1 = *(const bf16x8*)(qr + 32 + quad * 8);
        floatx4 e[4];
#pragma unroll
        for (int nt = 0; nt < 4; ++nt) e[nt] = vz;
#pragma unroll
        for (int nt = 0; nt < 4; ++nt) {
            bf16x8 bf = *(const bf16x8*)&Ks[(nt * 16 + l15) * 72 + quad * 8];
            e[nt] = __builtin_amdgcn_mfma_f32_16x16x32_bf16(a0, bf, e[nt], 0, 0, 0);
        }
#pragma unroll
        for (int nt = 0; nt < 4; ++nt) {
            bf16x8 bf = *(const bf16x8*)&Ks[(nt * 16 + l15) * 72 + 32 + quad * 8];
            e[nt] = __builtin_amdgcn_mfma_f32_16x16x32_bf16(a1, bf, e[nt], 0, 0, 0);
        }
#pragma unroll
        for (int nt = 0; nt < 4; ++nt) {
            uint2v p;
            p.x = pack_bf16(exp2f(e[nt][0]), exp2f(e[nt][1]));
            p.y = pack_bf16(exp2f(e[nt][2]), exp2f(e[nt][3]));
            *(uint2v*)&Ps[buf][(nt * 16 + l15) * 136 + il] = p;
        }
    };

    e_phase(0, 0);
    __syncthreads();

    for (int ib = 0; ib < 32; ++ib) {
        const int cur = ib & 1;
        // --- out += V' * P (m: 64 c-rows/wave, n=j 64, k=i 128) ---
#pragma unroll
        for (int ks = 0; ks < 4; ++ks) {
            bf16x8 af[4];
#pragma unroll
            for (int mi = 0; mi < 4; ++mi)
                af[mi] = *(const bf16x8*)(vb + (long)((wave * 4 + mi) * 16 + l15) * 4096 + ib * 128 + ks * 32 + quad * 8);
#pragma unroll
            for (int nt = 0; nt < 4; ++nt) {
                bf16x8 bf = *(const bf16x8*)&Ps[cur][(nt * 16 + l15) * 136 + ks * 32 + quad * 8];
#pragma unroll
                for (int mi = 0; mi < 4; ++mi)
                    oacc[mi][nt] = __builtin_amdgcn_mfma_f32_16x16x32_bf16(af[mi], bf, oacc[mi][nt], 0, 0, 0);
            }
        }
        if (ib < 31) e_phase(ib + 1, 1 - cur);
        __syncthreads();
    }

    // --- fused channel output: out += wco . coT^T (m=c, n=j, k=q 64) ---
    const unsigned short* cob = coT + ((long)b * 4096 + j0) * 64;
#pragma unroll
    for (int ks = 0; ks < 2; ++ks) {
        bf16x8 aw[4];
#pragma unroll
        for (int mi = 0; mi < 4; ++mi)
            aw[mi] = *(const bf16x8*)(wco + (long)((wave * 4 + mi) * 16 + l15) * 64 + ks * 32 + quad * 8);
#pragma unroll
        for (int nt = 0; nt < 4; ++nt) {
            bf16x8 bf = *(const bf16x8*)(cob + (long)(nt * 16 + l15) * 64 + ks * 32 + quad * 8);
#pragma unroll
            for (int mi = 0; mi < 4; ++mi)
                oacc[mi][nt] = __builtin_amdgcn_mfma_f32_16x16x32_bf16(aw[mi], bf, oacc[mi][nt], 0, 0, 0);
        }
    }
    // --- store (single write of out) ---
#pragma unroll
    for (int mi = 0; mi < 4; ++mi) {
        const int c = (wave * 4 + mi) * 16 + quad * 4;
#pragma unroll
        for (int nt = 0; nt < 4; ++nt) {
            const int j = j0 + nt * 16 + l15;
#pragma unroll
            for (int r = 0; r < 4; ++r)
                out[((long)b * 512 + c + r) * 4096 + j] = oacc[mi][nt][r] + co_b[c + r];
        }
    }
}

// ---------------------------------------------------------------------------
// x [B,512,4096] fp32 -> xT [B,4096,512] bf16 (64x64 LDS tile transpose)
// ---------------------------------------------------------------------------
__global__ __launch_bounds__(256) void transpose_x(
    const float* __restrict__ x, unsigned short* __restrict__ xT)
{
    __shared__ unsigned short T[64 * 66];
    const int b  = blockIdx.z;
    const int n0 = blockIdx.x * 64;
    const int c0 = blockIdx.y * 64;
    const int tid = threadIdx.x;
    const int r8 = tid >> 5;
    const int col2 = (tid & 31) * 2;
#pragma unroll
    for (int k = 0; k < 8; ++k) {
        const int c = r8 + k * 8;
        floatx2 v = *(const floatx2*)(x + ((long)(b * 512 + c0 + c)) * 4096 + n0 + col2);
        *(unsigned int*)&T[c * 66 + col2] = pack_bf16(v.x, v.y);
    }
    __syncthreads();
#pragma unroll
    for (int k = 0; k < 8; ++k) {
        const int n = r8 + k * 8;
        unsigned int pk = (unsigned int)T[col2 * 66 + n] | ((unsigned int)T[(col2 + 1) * 66 + n] << 16);
        *(unsigned int*)(xT + ((long)(b * 4096 + n0 + n)) * 512 + c0 + col2) = pk;
    }
}

// ---------------------------------------------------------------------------
// fp32 weights -> bf16, fused layouts:
//  wqkv [192][512] = [wq*LOG2E; wk; wcv],  wcqck [128][512] = [wcq; wck],
//  wv [512][512],  wco [512][64].  Biases: bqkv[192], bcqck[128] (fp32).
// ---------------------------------------------------------------------------
__global__ __launch_bounds__(256) void convert_weights(
    const float* __restrict__ pq_w, const float* __restrict__ pk_w,
    const float* __restrict__ pv_w, const float* __restrict__ cq_w,
    const float* __restrict__ ck_w, const float* __restrict__ cv_w,
    const float* __restrict__ co_w,
    const float* __restrict__ pq_b, const float* __restrict__ pk_b,
    const float* __restrict__ cv_b, const float* __restrict__ cq_b,
    const float* __restrict__ ck_b,
    unsigned short* __restrict__ dst, float* __restrict__ biases)
{
    const int total = 458752;
    const int gtid = blockIdx.x * 256 + threadIdx.x;
    for (int i = gtid; i < total; i += gridDim.x * 256) {
        float v;
        if (i < 98304) {
            int r = i >> 9, k = i & 511;
            if (r < 64)       v = pq_w[r * 512 + k] * LOG2E;
            else if (r < 128) v = pk_w[(r - 64) * 512 + k];
            else              v = cv_w[(r - 128) * 512 + k];
        } else if (i < 163840) {
            int j = i - 98304; int r = j >> 9, k = j & 511;
            v = (r < 64) ? cq_w[r * 512 + k] : ck_w[(r - 64) * 512 + k];
        } else if (i < 425984) v = pv_w[i - 163840];
        else                   v = co_w[i - 425984];
        dst[i] = f2bf(v);
    }
    if (gtid < 320) {
        float v;
        if (gtid < 64)       v = pq_b[gtid] * LOG2E;
        else if (gtid < 128) v = pk_b[gtid - 64];
        else if (gtid < 192) v = cv_b[gtid - 128];
        else if (gtid < 256) v = cq_b[gtid - 192];
        else                 v = ck_b[gtid - 256];
        biases[gtid] = v;
    }
}

// ---------------------------------------------------------------------------
// channel softmax over q (64 logits, fp32) -> c_attn bf16
// ---------------------------------------------------------------------------
__global__ __launch_bounds__(64) void chan_softmax(
    const float* __restrict__ ce, unsigned short* __restrict__ ca)
{
    const int p = blockIdx.x, b = blockIdx.y, q = threadIdx.x;
    const long base = ((long)b * 64 + p) * 64;
    float v = ce[base + q];
    float m = v;
#pragma unroll
    for (int s = 32; s >= 1; s >>= 1) m = fmaxf(m, __shfl_xor(m, s));
    float e = exp2f((v - m) * LOG2E);
    float sum = e;
#pragma unroll
    for (int s = 32; s >= 1; s >>= 1) sum += __shfl_xor(sum, s);
    ca[base + q] = f2bf(e / sum);
}

// ---------------------------------------------------------------------------
extern "C" void kernel_launch(void* const* d_in, const int* in_sizes, int n_in,
                              void* d_out, int out_size, void* d_ws, size_t ws_size,
                              hipStream_t stream) {
    const float* x    = (const float*)d_in[0];
    const float* pv_b = (const float*)d_in[6];
    const float* co_b = (const float*)d_in[14];
    float* out = (float*)d_out;
    char* ws = (char*)d_ws;

    // ws layout (bytes)
    constexpr long OFF_XT   = 0;                        // bf16 [8][4096][512]
    constexpr long OFF_QKV  = 33554432;                 // bf16 [8][4096][192] (q|k|cv)
    constexpr long OFF_VP   = OFF_QKV + 12582912;       // bf16 [8][512][4096] (v * rcp_l)
    constexpr long OFF_CQCK = OFF_VP + 33554432;        // bf16 [8][128][4096] (cq|ck)
    constexpr long OFF_COT  = OFF_CQCK + 8388608;       // bf16 [8][4096][64]
    constexpr long OFF_RCL  = OFF_COT + 4194304;        // fp32 [8][4096]
    constexpr long OFF_CE   = OFF_RCL + 131072;         // fp32 [8][64][64]
    constexpr long OFF_CAT  = OFF_CE + 131072;          // bf16 [8][64][64]
    constexpr long OFF_WB   = OFF_CAT + 65536;          // bf16 weights (458752)
    constexpr long OFF_BIAS = OFF_WB + 917504;          // fp32 [320]

    unsigned short* xT   = (unsigned short*)(ws + OFF_XT);
    unsigned short* qkvT = (unsigned short*)(ws + OFF_QKV);
    unsigned short* vP   = (unsigned short*)(ws + OFF_VP);
    unsigned short* cqck = (unsigned short*)(ws + OFF_CQCK);
    unsigned short* coT  = (unsigned short*)(ws + OFF_COT);
    float*          rcl  = (float*)(ws + OFF_RCL);
    float*          ce   = (float*)(ws + OFF_CE);
    unsigned short* cat  = (unsigned short*)(ws + OFF_CAT);
    unsigned short* wb   = (unsigned short*)(ws + OFF_WB);
    float*          bias = (float*)(ws + OFF_BIAS);
    unsigned short* wqkv  = wb;
    unsigned short* wcqck = wb + 98304;
    unsigned short* wv    = wb + 163840;
    unsigned short* wco   = wb + 425984;
    float* bqkv  = bias;
    float* bcqck = bias + 192;

    // 0) convert weights (+bias concat), transpose x
    convert_weights<<<dim3(64), 256, 0, stream>>>(
        (const float*)d_in[1], (const float*)d_in[3], (const float*)d_in[5],
        (const float*)d_in[7], (const float*)d_in[9], (const float*)d_in[11],
        (const float*)d_in[13],
        (const float*)d_in[2], (const float*)d_in[4], (const float*)d_in[12],
        (const float*)d_in[8], (const float*)d_in[10], wb, bias);
    transpose_x<<<dim3(64, 8, 8), 256, 0, stream>>>(x, xT);

    // 1) fused projections: qkvT [b][4096][192]; cqck [b][128][4096]
    tn_gemm<128, 192, true, false><<<dim3(1, 32, 8), 256, 0, stream>>>(
        xT, 512, 2097152L, wqkv, 512, 0L, qkvT, 192, 786432L,
        nullptr, bqkv, nullptr, 0L, 512, 1);
    tn_gemm<128, 128, true, false><<<dim3(32, 1, 8), 256, 0, stream>>>(
        wcqck, 512, 0L, xT, 512, 2097152L, cqck, 4096, 524288L,
        bcqck, nullptr, nullptr, 0L, 512, 1);

    // 2) softmax denominators -> rcp_l
    rowsum_kernel<<<dim3(8, 32), 512, 0, stream>>>(qkvT, rcl);

    // 3) v' = (Wv x + b) * rcp_l  (column scale by position)
    tn_gemm<128, 128, true, false><<<dim3(32, 4, 8), 256, 0, stream>>>(
        wv, 512, 0L, xT, 512, 2097152L, vP, 4096, 2097152L,
        pv_b, nullptr, rcl, 4096L, 512, 1);

    // 4) channel attention: c_energy (split-K atomic), softmax, c_outT
    hipMemsetAsync(ce, 0, 8 * 64 * 64 * sizeof(float), stream);
    tn_gemm<64, 64, false, true><<<dim3(1, 1, 64), 256, 0, stream>>>(
        cqck, 4096, 524288L, cqck + 262144, 4096, 524288L, ce, 64, 4096L,
        nullptr, nullptr, nullptr, 0L, 512, 8);
    chan_softmax<<<dim3(64, 8), 64, 0, stream>>>(ce, cat);
    tn_gemm<128, 64, true, false><<<dim3(1, 32, 8), 256, 0, stream>>>(
        qkvT + 128, 192, 786432L, cat, 64, 4096L, coT, 64, 262144L,
        nullptr, nullptr, nullptr, 0L, 64, 1);

    // 5) fused position attention + channel output epilogue -> out (1 write)
    pos_attn_kernel<<<dim3(8, 64), 512, 0, stream>>>(qkvT, vP, wco, coT, co_b, out);
}